// Round 17
// baseline (483.241 us; speedup 1.0000x reference)
//
#include <hip/hip_runtime.h>
#include <hip/hip_bf16.h>

typedef unsigned short u16;
typedef unsigned int u32;
typedef __attribute__((ext_vector_type(8))) short short8;
typedef __attribute__((ext_vector_type(4))) short shortx4;
typedef __attribute__((ext_vector_type(4))) float floatx4;

#define N_PTS 16384
#define N_GRID 4096
#define GPTS 512
#define HD 128
#define DEG 16
#define QB 16
#define EB 256
#define EBLK (N_PTS / QB)    // 1024 blocks (512 threads, 16 queries each, all 4 layers)

// fast silu: v_rcp_f32 instead of full-precision divide (rel err ~2^-22)
__device__ __forceinline__ float silu_f(float x) {
    return x * __builtin_amdgcn_rcpf(1.0f + __expf(-x));
}
__device__ __forceinline__ short f2bf(float x) { return (short)__bfloat16_as_ushort(__float2bfloat16(x)); }

__global__ void k_fillf(float* out, float v, int n) {
    int i = blockIdx.x * blockDim.x + threadIdx.x;
    if (i < n) out[i] = v;
}

// merged weight prep: wsT + nW1T/nW2T/W1midT/W1topT in one launch
__global__ void k_prepAll(const float* __restrict__ eW2, const float* __restrict__ nW1,
                          const float* __restrict__ nW2, const float* __restrict__ eW1,
                          short* __restrict__ wsT, short* __restrict__ nW1T,
                          short* __restrict__ nW2T, short* __restrict__ W1midT,
                          short* __restrict__ W1topT) {
    int idx = blockIdx.x * blockDim.x + threadIdx.x;
    if (idx < 65536) {
        int l = idx >> 14, rem = idx & 16383, f = rem >> 7, k = rem & 127;
        wsT[idx] = f2bf(eW2[l * 16384 + k * HD + f]);
        return;
    }
    idx -= 65536;
    if (idx < 3 * 32768) {
        int l = idx >> 15, r = idx & 32767, f = r >> 8, k = r & 255;
        nW1T[idx] = f2bf(nW1[l * 32768 + k * 128 + f]);
    } else if (idx < 3 * 32768 + 3 * 16384) {
        int j = idx - 3 * 32768;
        int l = j >> 14, r = j & 16383, f = r >> 7, k = r & 127;
        nW2T[j] = f2bf(nW2[l * 16384 + k * 128 + f]);
    } else if (idx < 3 * 32768 + 6 * 16384) {
        int j = idx - 3 * 32768 - 3 * 16384;
        int p = j >> 14, r = j & 16383, f = r >> 7, k = r & 127;
        W1midT[j] = f2bf(eW1[(p + 1) * 257 * 128 + (128 + k) * 128 + f]);
    } else if (idx < 3 * 32768 + 6 * 16384 + 4 * 16384) {
        int j = idx - 3 * 32768 - 6 * 16384;
        int l = j >> 14, r = j & 16383, f = r >> 7, k = r & 127;
        W1topT[j] = f2bf(eW1[l * 257 * 128 + k * 128 + f]);
    }
}

// ---------------- MFMA GEMM helpers ----------------
__device__ __forceinline__ void stageB(short* Bb, const short* src, int rowF4, int colF4, int tid) {
#pragma unroll
    for (int s = 0; s < 8; s++) {
        int idx = s * 256 + tid;
        int f = idx >> 4, c4 = idx & 15;
        float4 v = ((const float4*)src)[f * rowF4 + colF4 + c4];
        *(float4*)((char*)Bb + ((idx * 16) ^ ((f & 7) << 4))) = v;
    }
}

__device__ __forceinline__ void stageB512(short* Bb, const short* src, int rowF4, int colF4, int tid) {
#pragma unroll
    for (int s = 0; s < 4; s++) {
        int idx = s * 512 + tid;
        int f = idx >> 4, c4 = idx & 15;
        float4 v = ((const float4*)src)[f * rowF4 + colF4 + c4];
        *(float4*)((char*)Bb + ((idx * 16) ^ ((f & 7) << 4))) = v;
    }
}

__device__ __forceinline__ void nb_gemm(const short* X1, const short* Bb, floatx4* acc,
                                        int rowbase, int kOff, int quad, int c, int swz) {
#pragma unroll
    for (int ks = 0; ks < 4; ks++) {
        short8 a = *(const short8*)((const char*)X1 + rowbase + (((kOff + ks * 32 + quad * 8) * 2) ^ swz));
#pragma unroll
        for (int n = 0; n < 8; n++) {
            short8 b = *(const short8*)((const char*)Bb + ((((n * 16 + c) << 8) + (ks * 32 + quad * 8) * 2) ^ swz));
            acc[n] = __builtin_amdgcn_mfma_f32_16x16x32_bf16(a, b, acc[n], 0, 0, 0);
        }
    }
}

// 16-row GEMM: A = X[16 rows x (kOffX..kOffX+128)], B-col-tile = wid. One MFMA tile.
__device__ __forceinline__ void gemm16(const short* X, const short* Bb, floatx4& acc,
                                       int kOffX, int wid, int quad, int c, int swz) {
#pragma unroll
    for (int ks = 0; ks < 4; ks++) {
        int k = ks * 32 + quad * 8;
        short8 a = *(const short8*)((const char*)X + ((c * 512 + (kOffX + k) * 2) ^ swz));
        short8 b = *(const short8*)((const char*)Bb + ((((wid * 16 + c) << 8) + k * 2) ^ swz));
        acc = __builtin_amdgcn_mfma_f32_16x16x32_bf16(a, b, acc, 0, 0, 0);
    }
}

// ---------------- fused grid-node pipeline: 16 nodes/block, 256 blocks, ALL 4 layers ----------
// Re-tiled for parallelism (was 64 nodes / 64 blocks = 25% of CUs). Each wave owns
// 2 col-tiles (32 f-cols). X [16][128] bf16 row-swizzled; hgF f32; Bb staged per GEMM.
__global__ __launch_bounds__(256) void k_gm(
    const float* __restrict__ codes, float* __restrict__ Agall,
    const short* __restrict__ W1topT, const float* __restrict__ eb1,
    const short* __restrict__ nW1T, const float* __restrict__ nb1,
    const short* __restrict__ nW2T, const float* __restrict__ nb2) {
    __shared__ float hgF[16 * 128];  // 8KB f32 hg
    __shared__ short X[16 * 128];    // 4KB bf16, row-swizzled (row&7)<<4, 256B stride
    __shared__ short Bb[128 * 128];  // 32KB weights, f-swizzled
    int tid = threadIdx.x;
    int n0 = blockIdx.x * 16;
    int wid = tid >> 6, lane = tid & 63, quad = lane >> 4, c = lane & 15;
    const int swz = (c & 7) << 4;

    // init hgF + X from codes: 16 threads/row, 8 floats each
    {
        int q = tid >> 4, part = tid & 15;
        const float* src = &codes[(n0 + q) * HD + part * 8];
        float4 a = ((const float4*)src)[0];
        float4 b = ((const float4*)src)[1];
        *(float4*)&hgF[q * 128 + part * 8] = a;
        *(float4*)&hgF[q * 128 + part * 8 + 4] = b;
        short8 v;
        v[0] = f2bf(a.x); v[1] = f2bf(a.y); v[2] = f2bf(a.z); v[3] = f2bf(a.w);
        v[4] = f2bf(b.x); v[5] = f2bf(b.y); v[6] = f2bf(b.z); v[7] = f2bf(b.w);
        *(short8*)((char*)X + ((q * 256 + part * 16) ^ ((q & 7) << 4))) = v;
    }

    for (int L = 0; L < 4; L++) {
        stageB(Bb, W1topT + L * 16384, 16, 0, tid);
        __syncthreads();                 // X + Bb ready
        floatx4 acc[2];
        acc[0] = (floatx4)0.f; acc[1] = (floatx4)0.f;
#pragma unroll
        for (int ks = 0; ks < 4; ks++) {
            int k = ks * 32 + quad * 8;
            short8 a = *(const short8*)((const char*)X + ((c * 256 + k * 2) ^ swz));
#pragma unroll
            for (int j = 0; j < 2; j++) {
                int n = wid * 2 + j;
                short8 b = *(const short8*)((const char*)Bb + ((((n * 16 + c) << 8) + k * 2) ^ swz));
                acc[j] = __builtin_amdgcn_mfma_f32_16x16x32_bf16(a, b, acc[j], 0, 0, 0);
            }
        }
        float* Ag = Agall + (size_t)L * (N_GRID * HD);
#pragma unroll
        for (int j = 0; j < 2; j++) {
            int f = (wid * 2 + j) * 16 + c;
            float bv = eb1[L * 128 + f];
#pragma unroll
            for (int r = 0; r < 4; r++)
                Ag[(n0 + quad * 4 + r) * HD + f] = acc[j][r] + bv;
        }
        if (L == 3) break;

        __syncthreads();                 // GEMM1 Bb reads done
        stageB(Bb, nW1T + L * 32768, 32, 0, tid);   // h-half of Wn1
        __syncthreads();
        floatx4 a2[2];
        a2[0] = (floatx4)0.f; a2[1] = (floatx4)0.f;
#pragma unroll
        for (int ks = 0; ks < 4; ks++) {
            int k = ks * 32 + quad * 8;
            short8 a = *(const short8*)((const char*)X + ((c * 256 + k * 2) ^ swz));
#pragma unroll
            for (int j = 0; j < 2; j++) {
                int n = wid * 2 + j;
                short8 b = *(const short8*)((const char*)Bb + ((((n * 16 + c) << 8) + k * 2) ^ swz));
                a2[j] = __builtin_amdgcn_mfma_f32_16x16x32_bf16(a, b, a2[j], 0, 0, 0);
            }
        }
        __syncthreads();                 // all X + Bb reads done before overwrite
        // S overwrites X; stage Wn2
#pragma unroll
        for (int j = 0; j < 2; j++) {
            int f = (wid * 2 + j) * 16 + c;
            float b1v = nb1[L * 128 + f];
#pragma unroll
            for (int r = 0; r < 4; r++) {
                int row = quad * 4 + r;
                *(short*)((char*)X + ((row * 256 + f * 2) ^ ((row & 7) << 4))) =
                    f2bf(silu_f(a2[j][r] + b1v));
            }
        }
        stageB(Bb, nW2T + L * 16384, 16, 0, tid);
        __syncthreads();
        floatx4 a3[2];
        a3[0] = (floatx4)0.f; a3[1] = (floatx4)0.f;
#pragma unroll
        for (int ks = 0; ks < 4; ks++) {
            int k = ks * 32 + quad * 8;
            short8 a = *(const short8*)((const char*)X + ((c * 256 + k * 2) ^ swz));
#pragma unroll
            for (int j = 0; j < 2; j++) {
                int n = wid * 2 + j;
                short8 b = *(const short8*)((const char*)Bb + ((((n * 16 + c) << 8) + k * 2) ^ swz));
                a3[j] = __builtin_amdgcn_mfma_f32_16x16x32_bf16(a, b, a3[j], 0, 0, 0);
            }
        }
        // hgF += delta (+bn2); (row,f) writer unique
#pragma unroll
        for (int j = 0; j < 2; j++) {
            int f = (wid * 2 + j) * 16 + c;
            float b2v2 = nb2[L * 128 + f];
#pragma unroll
            for (int r = 0; r < 4; r++)
                hgF[(quad * 4 + r) * 128 + f] += a3[j][r] + b2v2;
        }
        __syncthreads();                 // GEMM3 X reads + hgF writes done
        // rebuild X = bf16(hgF)
        {
            int q = tid >> 4, part = tid & 15;
            float4 a = *(const float4*)&hgF[q * 128 + part * 8];
            float4 b = *(const float4*)&hgF[q * 128 + part * 8 + 4];
            short8 v;
            v[0] = f2bf(a.x); v[1] = f2bf(a.y); v[2] = f2bf(a.z); v[3] = f2bf(a.w);
            v[4] = f2bf(b.x); v[5] = f2bf(b.y); v[6] = f2bf(b.z); v[7] = f2bf(b.w);
            *(short8*)((char*)X + ((q * 256 + part * 16) ^ ((q & 7) << 4))) = v;
        }
        // next iteration's stageB + sync orders X writes before GEMM1 reads
    }
}

// ---------------- per-layer body of the mega kernel ----------------
// misc layout: sdist[256] scm[256] sdir[768] scoef[1280] (delta overlays misc[0..2047])
template <int OUTT, bool FIN>
__device__ __forceinline__ void edge_layer(
    int L, int q0, int tid, float4& hreg,
    float* misc, float* xs, int* sgi, short* Xn, float* BqF, short* lwsT,
    const float* __restrict__ Agall, const float* __restrict__ eW1,
    const short* __restrict__ wsT,
    const float* __restrict__ eb2all, const float* __restrict__ cWall,
    const float* __restrict__ cball,
    const float* __restrict__ fcW, const float* __restrict__ fcb,
    const float* __restrict__ gridp, const float* __restrict__ qp,
    float* __restrict__ out,
    const float* __restrict__ nb1all, const float* __restrict__ nb2all,
    const short* __restrict__ nW1T, const short* __restrict__ nW2T,
    const short* __restrict__ W1midT) {

    float* sdist = misc;
    float* scm   = misc + 256;
    float* sdir  = misc + 512;
    float* scoef = misc + 1280;
    float* delta = misc;             // reused after geometry/scoef consumed

    int wid = tid >> 6, lane = tid & 63, quad = lane >> 4, c = lane & 15;
    const int swz = (c & 7) << 4;
    const float* Ag = Agall + (size_t)L * (N_GRID * HD);
    const short* wsTL = wsT + L * 16384;
    const float* wdrow = eW1 + L * 257 * 128 + 256 * 128;
    const float* b2v = eb2all + L * 128;
    const float* Wc = FIN ? fcW : (cWall + L * 128);
    const float* cbp = FIN ? fcb : (cball + L);

    // stage We2 -> lwsT swizzled (prev layer's lwsT reads done at end-of-layer barrier)
    {
        const float4* src = (const float4*)wsTL;
#pragma unroll
        for (int s = 0; s < 4; s++) {
            int idx = s * 512 + tid;
            int byte = idx << 4;
            int sw = byte ^ (((byte >> 8) & 7) << 4);
            *(float4*)((char*)lwsT + sw) = src[idx];
        }
    }
    // geometry from current xs
    if (tid < EB) {
        int e = tid, q = e >> 4;
        int gi = sgi[e];
        int gl = gi & (GPTS - 1);
        float r0 = gridp[gl * 3 + 0] - xs[q * 3 + 0];
        float r1 = gridp[gl * 3 + 1] - xs[q * 3 + 1];
        float r2 = gridp[gl * 3 + 2] - xs[q * 3 + 2];
        float dist = sqrtf(r0 * r0 + r1 * r1 + r2 * r2);
        float inv = 1.0f / (dist + 1e-8f);
        sdist[e] = dist;
        sdir[0 * EB + e] = r0 * inv;
        sdir[1 * EB + e] = r1 * inv;
        sdir[2 * EB + e] = r2 * inv;
        float cw = 0.5f * (__cosf(dist * 0.31415926535897931f) + 1.0f);
        scm[e] = (dist <= 10.0f) ? cw : 0.0f;
    }
    __syncthreads();

    int gi_[2]; float dist_[2];
#pragma unroll
    for (int mi = 0; mi < 2; mi++) {
        int e = (wid * 2 + mi) * 16 + c;
        gi_[mi] = sgi[e];
        dist_[mi] = sdist[e];
    }

    floatx4 acc[2][8];
#pragma unroll
    for (int mi = 0; mi < 2; mi++)
#pragma unroll
        for (int n = 0; n < 8; n++) acc[mi][n] = (floatx4)0.f;

#pragma unroll
    for (int ch = 0; ch < 4; ch++) {
        int kb = ch * 32 + quad * 8;
        float4 wd0 = *(const float4*)(wdrow + kb);
        float4 wd1 = *(const float4*)(wdrow + kb + 4);
        short8 afr[2];
#pragma unroll
        for (int mi = 0; mi < 2; mi++) {
            int q = wid * 2 + mi;
            float dist = dist_[mi];
            const float4* ap = (const float4*)(Ag + gi_[mi] * HD + kb);
            float4 a0 = ap[0], a1 = ap[1];
            const float4* bp4 = (const float4*)(BqF + q * HD + kb);   // LDS Bq
            float4 b0 = bp4[0], b1 = bp4[1];
            short8 v;
            v[0] = f2bf(silu_f(a0.x + b0.x + dist * wd0.x));
            v[1] = f2bf(silu_f(a0.y + b0.y + dist * wd0.y));
            v[2] = f2bf(silu_f(a0.z + b0.z + dist * wd0.z));
            v[3] = f2bf(silu_f(a0.w + b0.w + dist * wd0.w));
            v[4] = f2bf(silu_f(a1.x + b1.x + dist * wd1.x));
            v[5] = f2bf(silu_f(a1.y + b1.y + dist * wd1.y));
            v[6] = f2bf(silu_f(a1.z + b1.z + dist * wd1.z));
            v[7] = f2bf(silu_f(a1.w + b1.w + dist * wd1.w));
            afr[mi] = v;
        }
#pragma unroll
        for (int n = 0; n < 8; n++) {
            int byte = ((n * 16 + c) << 8) + (kb << 1);
            short8 bfr = *(const short8*)((const char*)lwsT + (byte ^ swz));
            acc[0][n] = __builtin_amdgcn_mfma_f32_16x16x32_bf16(afr[0], bfr, acc[0][n], 0, 0, 0);
            acc[1][n] = __builtin_amdgcn_mfma_f32_16x16x32_bf16(afr[1], bfr, acc[1][n], 0, 0, 0);
        }
    }
    __syncthreads();   // all BqF reads done before Xn (overlaid) m_aggr writes

#pragma unroll
    for (int mi = 0; mi < 2; mi++) {
        int q = wid * 2 + mi;
        int ebase = q * 16;
        float cmr[4];
#pragma unroll
        for (int r = 0; r < 4; r++) cmr[r] = scm[ebase + quad * 4 + r];
        float apc[4][OUTT];
#pragma unroll
        for (int r = 0; r < 4; r++)
#pragma unroll
            for (int t = 0; t < OUTT; t++) apc[r][t] = 0.f;
#pragma unroll
        for (int n = 0; n < 8; n++) {
            int f = n * 16 + c;
            float be2v = b2v[f];
            float wcv[OUTT];
            if (FIN) {
#pragma unroll
                for (int t = 0; t < OUTT; t++) wcv[t] = Wc[f * 5 + t];
            } else {
                wcv[0] = Wc[f];
            }
            float cs = 0.f;
#pragma unroll
            for (int r = 0; r < 4; r++) {
                float v = silu_f(acc[mi][n][r] + be2v) * cmr[r];
                cs += v;
#pragma unroll
                for (int t = 0; t < OUTT; t++) apc[r][t] += v * wcv[t];
            }
            cs += __shfl_xor(cs, 16, 64);
            cs += __shfl_xor(cs, 32, 64);
            if (!FIN && lane < 16)
                *(short*)((char*)Xn + ((q * 512 + (128 + f) * 2) ^ ((q & 7) << 4))) =
                    f2bf(cs * 0.0625f);
        }
#pragma unroll
        for (int t = 0; t < OUTT; t++) {
#pragma unroll
            for (int r = 0; r < 4; r++) {
                float v = apc[r][t];
                v += __shfl_xor(v, 1, 64);
                v += __shfl_xor(v, 2, 64);
                v += __shfl_xor(v, 4, 64);
                v += __shfl_xor(v, 8, 64);
                if (c == 0) scoef[(ebase + quad * 4 + r) * OUTT + t] = v;
            }
        }
    }
    __syncthreads();   // scoef + Xn m_aggr ready; lwsT K-loop reads done

    if (tid < QB * 3 * OUTT) {
        int qq = tid / (3 * OUTT), rem = tid % (3 * OUTT), t = rem / 3, c2 = rem % 3;
        float cbv = cbp[t];
        float s = 0.f;
#pragma unroll 4
        for (int r = 0; r < 16; r++) {
            int ee = qq * 16 + r;
            s += (scoef[ee * OUTT + t] + cbv) * sdir[c2 * EB + ee];
        }
        float dd = s * 0.0625f;
        if (FIN) out[(q0 + qq) * 15 + t * 3 + c2] = xs[qq * 3 + c2] + dd - qp[(q0 + qq) * 3 + c2];
        else xs[qq * 3 + c2] = xs[qq * 3 + c2] + dd;
    }
    if (FIN) return;

    // ---- node MLP (block-local) ----
    // stage h (regs -> bf16) into Xn k0..127
    {
        int q = tid >> 5, f0 = (tid & 31) * 4;
        shortx4 v;
        v[0] = f2bf(hreg.x); v[1] = f2bf(hreg.y); v[2] = f2bf(hreg.z); v[3] = f2bf(hreg.w);
        *(shortx4*)((char*)Xn + ((q * 512 + f0 * 2) ^ ((q & 7) << 4))) = v;
    }
    stageB512(lwsT, nW1T + L * 32768, 32, 0, tid);     // Wn1 k-half 0 (h)
    __syncthreads();

    floatx4 acc1 = (floatx4)0.f;
    gemm16(Xn, lwsT, acc1, 0, wid, quad, c, swz);      // GEMM1a: h-half
    __syncthreads();
    stageB512(lwsT, nW1T + L * 32768, 32, 16, tid);    // Wn1 k-half 1 (m_aggr)
    __syncthreads();
    gemm16(Xn, lwsT, acc1, 128, wid, quad, c, swz);    // GEMM1b (accumulate)
    __syncthreads();                                    // Xn k128 reads done

    {
        int f = wid * 16 + c;
        float b1v = nb1all[L * 128 + f];
#pragma unroll
        for (int r = 0; r < 4; r++) {
            int q = quad * 4 + r;
            *(short*)((char*)Xn + ((q * 512 + (128 + f) * 2) ^ ((q & 7) << 4))) =
                f2bf(silu_f(acc1[r] + b1v));
        }
    }
    stageB512(lwsT, nW2T + L * 16384, 16, 0, tid);
    __syncthreads();

    floatx4 acc2 = (floatx4)0.f;
    gemm16(Xn, lwsT, acc2, 128, wid, quad, c, swz);    // GEMM2: S · Wn2
    __syncthreads();                                    // lwsT reads done

    {
        int f = wid * 16 + c;
        float b2 = nb2all[L * 128 + f];
#pragma unroll
        for (int r = 0; r < 4; r++)
            delta[(quad * 4 + r) * 128 + f] = acc2[r] + b2;
    }
    stageB512(lwsT, W1midT + L * 16384, 16, 0, tid);
    __syncthreads();

    {   // owner updates h register, writes bf16(h') to Xn k0..127
        int q = tid >> 5, f0 = (tid & 31) * 4;
        hreg.x += delta[q * 128 + f0 + 0];
        hreg.y += delta[q * 128 + f0 + 1];
        hreg.z += delta[q * 128 + f0 + 2];
        hreg.w += delta[q * 128 + f0 + 3];
        shortx4 v;
        v[0] = f2bf(hreg.x); v[1] = f2bf(hreg.y); v[2] = f2bf(hreg.z); v[3] = f2bf(hreg.w);
        *(shortx4*)((char*)Xn + ((q * 512 + f0 * 2) ^ ((q & 7) << 4))) = v;
    }
    __syncthreads();

    floatx4 acc3 = (floatx4)0.f;
    gemm16(Xn, lwsT, acc3, 0, wid, quad, c, swz);      // GEMM3: h' · W1mid
    __syncthreads();                                    // Xn reads done before BqF overlay write
    {
        int f = wid * 16 + c;
#pragma unroll
        for (int r = 0; r < 4; r++)
            BqF[(quad * 4 + r) * 128 + f] = acc3[r];
    }
    __syncthreads();                                    // end of layer: xs/BqF/lwsT ready
}

// ---------------- mega kernel: all 4 edge layers + node MLPs for 16 queries ----------------
// launch_bounds (512,3): round-10 precedent shows this body fits VGPR=80 spill-free;
// LDS 51.5KB x 3 = 158KB fits -> 24 waves/CU (was 16 at (512,2)/VGPR=128).
// (512,4)->VGPR 64 spilled 222MB (rounds 11/14). WRITE_SIZE is the spill tripwire.
__global__ __launch_bounds__(512, 3) void k_mega(
    const float* __restrict__ Agall, const float* __restrict__ eW1,
    const short* __restrict__ wsT,
    const float* __restrict__ eb2, const float* __restrict__ cW,
    const float* __restrict__ cb,
    const float* __restrict__ fcW, const float* __restrict__ fcb,
    const int* __restrict__ erow, const float* __restrict__ gridp,
    const float* __restrict__ qp, float* __restrict__ out,
    const float* __restrict__ nb1, const float* __restrict__ nb2,
    const short* __restrict__ nW1T, const short* __restrict__ nW2T,
    const short* __restrict__ W1midT) {
    __shared__ float misc[2560];       // 10.25KB scratch (delta overlays)
    __shared__ float xs[48];
    __shared__ int sgi[256];
    __shared__ union { short xn[16 * 256]; float bq[16 * 128]; } XB;  // 8KB overlay
    __shared__ short lwsT[HD * HD];    // 32KB
    int tid = threadIdx.x;
    // XCD-chunked swizzle (bijective: EBLK % 8 == 0)
    int sb = (blockIdx.x & 7) * (EBLK / 8) + (blockIdx.x >> 3);
    int q0 = sb * QB;

    if (tid < QB * 3) xs[tid] = qp[q0 * 3 + tid];
    if (tid < EB) sgi[tid] = erow[q0 * DEG + tid] - N_PTS;
    for (int i = tid; i < 16 * 128; i += 512) XB.bq[i] = 0.0f;   // Bq(0) = 0
    float4 hreg = make_float4(0.f, 0.f, 0.f, 0.f);               // h(0) = 0
    __syncthreads();

    for (int L = 0; L < 3; L++)
        edge_layer<1, false>(L, q0, tid, hreg, misc, xs, sgi, XB.xn, XB.bq, lwsT,
                             Agall, eW1, wsT, eb2, cW, cb, fcW, fcb, gridp, qp, out,
                             nb1, nb2, nW1T, nW2T, W1midT);
    edge_layer<5, true>(3, q0, tid, hreg, misc, xs, sgi, XB.xn, XB.bq, lwsT,
                        Agall, eW1, wsT, eb2, cW, cb, fcW, fcb, gridp, qp, out,
                        nb1, nb2, nW1T, nW2T, W1midT);
}

extern "C" void kernel_launch(void* const* d_in, const int* in_sizes, int n_in,
                              void* d_out, int out_size, void* d_ws, size_t ws_size,
                              hipStream_t stream) {
    float* out = (float*)d_out;
    int fill_blocks = (out_size + 255) / 256;

    static const int exp_sz[16] = { 49152, 524288, 1536, 131584, 512, 65536, 512, 384,
                                    3, 640, 5, 131072, 512, 65536, 512, 524288 };
    bool ok = (n_in == 16);
    for (int i = 0; ok && i < 16; i++) if (in_sizes[i] != exp_sz[i]) ok = false;
    if (!ok || ws_size < (size_t)40 * 1024 * 1024) {
        k_fillf<<<fill_blocks, 256, 0, stream>>>(out, 777.0f, out_size);
        return;
    }

    const float* qp    = (const float*)d_in[0];
    const float* codes = (const float*)d_in[1];
    const float* gridp = (const float*)d_in[2];
    const float* eW1   = (const float*)d_in[3];
    const float* eb1   = (const float*)d_in[4];
    const float* eW2   = (const float*)d_in[5];
    const float* eb2   = (const float*)d_in[6];
    const float* cW    = (const float*)d_in[7];
    const float* cb    = (const float*)d_in[8];
    const float* fcW   = (const float*)d_in[9];
    const float* fcb   = (const float*)d_in[10];
    const float* nW1   = (const float*)d_in[11];
    const float* nb1   = (const float*)d_in[12];
    const float* nW2   = (const float*)d_in[13];
    const float* nb2   = (const float*)d_in[14];
    const int*   erow  = (const int*)d_in[15];

    float* ws = (float*)d_ws;
    float* Agall = ws;  ws += 4 * N_GRID * HD;
    short* wsT    = (short*)ws;        // 4 x 16384
    short* nW1T   = wsT + 65536;       // 3 x 32768
    short* nW2T   = nW1T + 98304;      // 3 x 16384
    short* W1midT = nW2T + 49152;      // 3 x 16384
    short* W1topT = W1midT + 49152;    // 4 x 16384

    k_prepAll<<<(65536 + 3 * 32768 + 6 * 16384 + 4 * 16384 + 255) / 256, 256, 0, stream>>>(
        eW2, nW1, nW2, eW1, wsT, nW1T, nW2T, W1midT, W1topT);

    // fused grid-node pipeline: one launch, all 4 layers, 256 blocks (full GPU)
    k_gm<<<N_GRID / 16, 256, 0, stream>>>(codes, Agall, W1topT, eb1,
                                          nW1T, nb1, nW2T, nb2);

    // one launch: all 4 edge layers + node MLPs (per-query state block-local)
    k_mega<<<EBLK, 512, 0, stream>>>(
        Agall, eW1, wsT, eb2, cW, cb, fcW, fcb, erow, gridp, qp, out,
        nb1, nb2, nW1T, nW2T, W1midT);
}

// Round 18
// 324.660 us; speedup vs baseline: 1.4885x; 1.4885x over previous
//
#include <hip/hip_runtime.h>
#include <hip/hip_bf16.h>

typedef unsigned short u16;
typedef unsigned int u32;
typedef __attribute__((ext_vector_type(8))) short short8;
typedef __attribute__((ext_vector_type(4))) short shortx4;
typedef __attribute__((ext_vector_type(4))) float floatx4;

#define N_PTS 16384
#define N_GRID 4096
#define GPTS 512
#define HD 128
#define DEG 16
#define QB 16
#define EB 256
#define EBLK (N_PTS / QB)    // 1024 blocks (512 threads, 16 queries each, all 4 layers)

// fast silu: v_rcp_f32 instead of full-precision divide (rel err ~2^-22)
__device__ __forceinline__ float silu_f(float x) {
    return x * __builtin_amdgcn_rcpf(1.0f + __expf(-x));
}
__device__ __forceinline__ short f2bf(float x) { return (short)__bfloat16_as_ushort(__float2bfloat16(x)); }

__global__ void k_fillf(float* out, float v, int n) {
    int i = blockIdx.x * blockDim.x + threadIdx.x;
    if (i < n) out[i] = v;
}

// merged weight prep: wsT + nW1T/nW2T/W1midT/W1topT in one launch
__global__ void k_prepAll(const float* __restrict__ eW2, const float* __restrict__ nW1,
                          const float* __restrict__ nW2, const float* __restrict__ eW1,
                          short* __restrict__ wsT, short* __restrict__ nW1T,
                          short* __restrict__ nW2T, short* __restrict__ W1midT,
                          short* __restrict__ W1topT) {
    int idx = blockIdx.x * blockDim.x + threadIdx.x;
    if (idx < 65536) {
        int l = idx >> 14, rem = idx & 16383, f = rem >> 7, k = rem & 127;
        wsT[idx] = f2bf(eW2[l * 16384 + k * HD + f]);
        return;
    }
    idx -= 65536;
    if (idx < 3 * 32768) {
        int l = idx >> 15, r = idx & 32767, f = r >> 8, k = r & 255;
        nW1T[idx] = f2bf(nW1[l * 32768 + k * 128 + f]);
    } else if (idx < 3 * 32768 + 3 * 16384) {
        int j = idx - 3 * 32768;
        int l = j >> 14, r = j & 16383, f = r >> 7, k = r & 127;
        nW2T[j] = f2bf(nW2[l * 16384 + k * 128 + f]);
    } else if (idx < 3 * 32768 + 6 * 16384) {
        int j = idx - 3 * 32768 - 3 * 16384;
        int p = j >> 14, r = j & 16383, f = r >> 7, k = r & 127;
        W1midT[j] = f2bf(eW1[(p + 1) * 257 * 128 + (128 + k) * 128 + f]);
    } else if (idx < 3 * 32768 + 6 * 16384 + 4 * 16384) {
        int j = idx - 3 * 32768 - 6 * 16384;
        int l = j >> 14, r = j & 16383, f = r >> 7, k = r & 127;
        W1topT[j] = f2bf(eW1[l * 257 * 128 + k * 128 + f]);
    }
}

// ---------------- MFMA GEMM helpers ----------------
__device__ __forceinline__ void stageB(short* Bb, const short* src, int rowF4, int colF4, int tid) {
#pragma unroll
    for (int s = 0; s < 8; s++) {
        int idx = s * 256 + tid;
        int f = idx >> 4, c4 = idx & 15;
        float4 v = ((const float4*)src)[f * rowF4 + colF4 + c4];
        *(float4*)((char*)Bb + ((idx * 16) ^ ((f & 7) << 4))) = v;
    }
}

__device__ __forceinline__ void stageB512(short* Bb, const short* src, int rowF4, int colF4, int tid) {
#pragma unroll
    for (int s = 0; s < 4; s++) {
        int idx = s * 512 + tid;
        int f = idx >> 4, c4 = idx & 15;
        float4 v = ((const float4*)src)[f * rowF4 + colF4 + c4];
        *(float4*)((char*)Bb + ((idx * 16) ^ ((f & 7) << 4))) = v;
    }
}

__device__ __forceinline__ void nb_gemm(const short* X1, const short* Bb, floatx4* acc,
                                        int rowbase, int kOff, int quad, int c, int swz) {
#pragma unroll
    for (int ks = 0; ks < 4; ks++) {
        short8 a = *(const short8*)((const char*)X1 + rowbase + (((kOff + ks * 32 + quad * 8) * 2) ^ swz));
#pragma unroll
        for (int n = 0; n < 8; n++) {
            short8 b = *(const short8*)((const char*)Bb + ((((n * 16 + c) << 8) + (ks * 32 + quad * 8) * 2) ^ swz));
            acc[n] = __builtin_amdgcn_mfma_f32_16x16x32_bf16(a, b, acc[n], 0, 0, 0);
        }
    }
}

// 16-row GEMM: A = X[16 rows x (kOffX..kOffX+128)], B-col-tile = wid. One MFMA tile.
__device__ __forceinline__ void gemm16(const short* X, const short* Bb, floatx4& acc,
                                       int kOffX, int wid, int quad, int c, int swz) {
#pragma unroll
    for (int ks = 0; ks < 4; ks++) {
        int k = ks * 32 + quad * 8;
        short8 a = *(const short8*)((const char*)X + ((c * 512 + (kOffX + k) * 2) ^ swz));
        short8 b = *(const short8*)((const char*)Bb + ((((wid * 16 + c) << 8) + k * 2) ^ swz));
        acc = __builtin_amdgcn_mfma_f32_16x16x32_bf16(a, b, acc, 0, 0, 0);
    }
}

// ---------------- fused grid-node pipeline: 16 nodes/block, 256 blocks, ALL 4 layers ----------
__global__ __launch_bounds__(256) void k_gm(
    const float* __restrict__ codes, float* __restrict__ Agall,
    const short* __restrict__ W1topT, const float* __restrict__ eb1,
    const short* __restrict__ nW1T, const float* __restrict__ nb1,
    const short* __restrict__ nW2T, const float* __restrict__ nb2) {
    __shared__ float hgF[16 * 128];  // 8KB f32 hg
    __shared__ short X[16 * 128];    // 4KB bf16, row-swizzled (row&7)<<4, 256B stride
    __shared__ short Bb[128 * 128];  // 32KB weights, f-swizzled
    int tid = threadIdx.x;
    int n0 = blockIdx.x * 16;
    int wid = tid >> 6, lane = tid & 63, quad = lane >> 4, c = lane & 15;
    const int swz = (c & 7) << 4;

    // init hgF + X from codes: 16 threads/row, 8 floats each
    {
        int q = tid >> 4, part = tid & 15;
        const float* src = &codes[(n0 + q) * HD + part * 8];
        float4 a = ((const float4*)src)[0];
        float4 b = ((const float4*)src)[1];
        *(float4*)&hgF[q * 128 + part * 8] = a;
        *(float4*)&hgF[q * 128 + part * 8 + 4] = b;
        short8 v;
        v[0] = f2bf(a.x); v[1] = f2bf(a.y); v[2] = f2bf(a.z); v[3] = f2bf(a.w);
        v[4] = f2bf(b.x); v[5] = f2bf(b.y); v[6] = f2bf(b.z); v[7] = f2bf(b.w);
        *(short8*)((char*)X + ((q * 256 + part * 16) ^ ((q & 7) << 4))) = v;
    }

    for (int L = 0; L < 4; L++) {
        stageB(Bb, W1topT + L * 16384, 16, 0, tid);
        __syncthreads();                 // X + Bb ready
        floatx4 acc[2];
        acc[0] = (floatx4)0.f; acc[1] = (floatx4)0.f;
#pragma unroll
        for (int ks = 0; ks < 4; ks++) {
            int k = ks * 32 + quad * 8;
            short8 a = *(const short8*)((const char*)X + ((c * 256 + k * 2) ^ swz));
#pragma unroll
            for (int j = 0; j < 2; j++) {
                int n = wid * 2 + j;
                short8 b = *(const short8*)((const char*)Bb + ((((n * 16 + c) << 8) + k * 2) ^ swz));
                acc[j] = __builtin_amdgcn_mfma_f32_16x16x32_bf16(a, b, acc[j], 0, 0, 0);
            }
        }
        float* Ag = Agall + (size_t)L * (N_GRID * HD);
#pragma unroll
        for (int j = 0; j < 2; j++) {
            int f = (wid * 2 + j) * 16 + c;
            float bv = eb1[L * 128 + f];
#pragma unroll
            for (int r = 0; r < 4; r++)
                Ag[(n0 + quad * 4 + r) * HD + f] = acc[j][r] + bv;
        }
        if (L == 3) break;

        __syncthreads();                 // GEMM1 Bb reads done
        stageB(Bb, nW1T + L * 32768, 32, 0, tid);   // h-half of Wn1
        __syncthreads();
        floatx4 a2[2];
        a2[0] = (floatx4)0.f; a2[1] = (floatx4)0.f;
#pragma unroll
        for (int ks = 0; ks < 4; ks++) {
            int k = ks * 32 + quad * 8;
            short8 a = *(const short8*)((const char*)X + ((c * 256 + k * 2) ^ swz));
#pragma unroll
            for (int j = 0; j < 2; j++) {
                int n = wid * 2 + j;
                short8 b = *(const short8*)((const char*)Bb + ((((n * 16 + c) << 8) + k * 2) ^ swz));
                a2[j] = __builtin_amdgcn_mfma_f32_16x16x32_bf16(a, b, a2[j], 0, 0, 0);
            }
        }
        __syncthreads();                 // all X + Bb reads done before overwrite
        // S overwrites X; stage Wn2
#pragma unroll
        for (int j = 0; j < 2; j++) {
            int f = (wid * 2 + j) * 16 + c;
            float b1v = nb1[L * 128 + f];
#pragma unroll
            for (int r = 0; r < 4; r++) {
                int row = quad * 4 + r;
                *(short*)((char*)X + ((row * 256 + f * 2) ^ ((row & 7) << 4))) =
                    f2bf(silu_f(a2[j][r] + b1v));
            }
        }
        stageB(Bb, nW2T + L * 16384, 16, 0, tid);
        __syncthreads();
        floatx4 a3[2];
        a3[0] = (floatx4)0.f; a3[1] = (floatx4)0.f;
#pragma unroll
        for (int ks = 0; ks < 4; ks++) {
            int k = ks * 32 + quad * 8;
            short8 a = *(const short8*)((const char*)X + ((c * 256 + k * 2) ^ swz));
#pragma unroll
            for (int j = 0; j < 2; j++) {
                int n = wid * 2 + j;
                short8 b = *(const short8*)((const char*)Bb + ((((n * 16 + c) << 8) + k * 2) ^ swz));
                a3[j] = __builtin_amdgcn_mfma_f32_16x16x32_bf16(a, b, a3[j], 0, 0, 0);
            }
        }
        // hgF += delta (+bn2); (row,f) writer unique
#pragma unroll
        for (int j = 0; j < 2; j++) {
            int f = (wid * 2 + j) * 16 + c;
            float b2v2 = nb2[L * 128 + f];
#pragma unroll
            for (int r = 0; r < 4; r++)
                hgF[(quad * 4 + r) * 128 + f] += a3[j][r] + b2v2;
        }
        __syncthreads();                 // GEMM3 X reads + hgF writes done
        // rebuild X = bf16(hgF)
        {
            int q = tid >> 4, part = tid & 15;
            float4 a = *(const float4*)&hgF[q * 128 + part * 8];
            float4 b = *(const float4*)&hgF[q * 128 + part * 8 + 4];
            short8 v;
            v[0] = f2bf(a.x); v[1] = f2bf(a.y); v[2] = f2bf(a.z); v[3] = f2bf(a.w);
            v[4] = f2bf(b.x); v[5] = f2bf(b.y); v[6] = f2bf(b.z); v[7] = f2bf(b.w);
            *(short8*)((char*)X + ((q * 256 + part * 16) ^ ((q & 7) << 4))) = v;
        }
        // next iteration's stageB + sync orders X writes before GEMM1 reads
    }
}

// ---------------- per-layer body of the mega kernel ----------------
// misc layout: sdist[256] scm[256] sdir[768] scoef[1280] (delta overlays misc[0..2047])
template <int OUTT, bool FIN>
__device__ __forceinline__ void edge_layer(
    int L, int q0, int tid, float4& hreg,
    float* misc, float* xs, int* sgi, short* Xn, float* BqF, short* lwsT,
    const float* __restrict__ Agall, const float* __restrict__ eW1,
    const short* __restrict__ wsT,
    const float* __restrict__ eb2all, const float* __restrict__ cWall,
    const float* __restrict__ cball,
    const float* __restrict__ fcW, const float* __restrict__ fcb,
    const float* __restrict__ gridp, const float* __restrict__ qp,
    float* __restrict__ out,
    const float* __restrict__ nb1all, const float* __restrict__ nb2all,
    const short* __restrict__ nW1T, const short* __restrict__ nW2T,
    const short* __restrict__ W1midT) {

    float* sdist = misc;
    float* scm   = misc + 256;
    float* sdir  = misc + 512;
    float* scoef = misc + 1280;
    float* delta = misc;             // reused after geometry/scoef consumed

    int wid = tid >> 6, lane = tid & 63, quad = lane >> 4, c = lane & 15;
    const int swz = (c & 7) << 4;
    const float* Ag = Agall + (size_t)L * (N_GRID * HD);
    const short* wsTL = wsT + L * 16384;
    const float* wdrow = eW1 + L * 257 * 128 + 256 * 128;
    const float* b2v = eb2all + L * 128;
    const float* Wc = FIN ? fcW : (cWall + L * 128);
    const float* cbp = FIN ? fcb : (cball + L);

    // stage We2 -> lwsT swizzled (prev layer's lwsT reads done at end-of-layer barrier)
    {
        const float4* src = (const float4*)wsTL;
#pragma unroll
        for (int s = 0; s < 4; s++) {
            int idx = s * 512 + tid;
            int byte = idx << 4;
            int sw = byte ^ (((byte >> 8) & 7) << 4);
            *(float4*)((char*)lwsT + sw) = src[idx];
        }
    }
    // geometry from current xs
    if (tid < EB) {
        int e = tid, q = e >> 4;
        int gi = sgi[e];
        int gl = gi & (GPTS - 1);
        float r0 = gridp[gl * 3 + 0] - xs[q * 3 + 0];
        float r1 = gridp[gl * 3 + 1] - xs[q * 3 + 1];
        float r2 = gridp[gl * 3 + 2] - xs[q * 3 + 2];
        float dist = sqrtf(r0 * r0 + r1 * r1 + r2 * r2);
        float inv = 1.0f / (dist + 1e-8f);
        sdist[e] = dist;
        sdir[0 * EB + e] = r0 * inv;
        sdir[1 * EB + e] = r1 * inv;
        sdir[2 * EB + e] = r2 * inv;
        float cw = 0.5f * (__cosf(dist * 0.31415926535897931f) + 1.0f);
        scm[e] = (dist <= 10.0f) ? cw : 0.0f;
    }
    __syncthreads();

    int gi_[2]; float dist_[2];
#pragma unroll
    for (int mi = 0; mi < 2; mi++) {
        int e = (wid * 2 + mi) * 16 + c;
        gi_[mi] = sgi[e];
        dist_[mi] = sdist[e];
    }

    floatx4 acc[2][8];
#pragma unroll
    for (int mi = 0; mi < 2; mi++)
#pragma unroll
        for (int n = 0; n < 8; n++) acc[mi][n] = (floatx4)0.f;

#pragma unroll
    for (int ch = 0; ch < 4; ch++) {
        int kb = ch * 32 + quad * 8;
        float4 wd0 = *(const float4*)(wdrow + kb);
        float4 wd1 = *(const float4*)(wdrow + kb + 4);
        short8 afr[2];
#pragma unroll
        for (int mi = 0; mi < 2; mi++) {
            int q = wid * 2 + mi;
            float dist = dist_[mi];
            const float4* ap = (const float4*)(Ag + gi_[mi] * HD + kb);
            float4 a0 = ap[0], a1 = ap[1];
            const float4* bp4 = (const float4*)(BqF + q * HD + kb);   // LDS Bq
            float4 b0 = bp4[0], b1 = bp4[1];
            short8 v;
            v[0] = f2bf(silu_f(a0.x + b0.x + dist * wd0.x));
            v[1] = f2bf(silu_f(a0.y + b0.y + dist * wd0.y));
            v[2] = f2bf(silu_f(a0.z + b0.z + dist * wd0.z));
            v[3] = f2bf(silu_f(a0.w + b0.w + dist * wd0.w));
            v[4] = f2bf(silu_f(a1.x + b1.x + dist * wd1.x));
            v[5] = f2bf(silu_f(a1.y + b1.y + dist * wd1.y));
            v[6] = f2bf(silu_f(a1.z + b1.z + dist * wd1.z));
            v[7] = f2bf(silu_f(a1.w + b1.w + dist * wd1.w));
            afr[mi] = v;
        }
#pragma unroll
        for (int n = 0; n < 8; n++) {
            int byte = ((n * 16 + c) << 8) + (kb << 1);
            short8 bfr = *(const short8*)((const char*)lwsT + (byte ^ swz));
            acc[0][n] = __builtin_amdgcn_mfma_f32_16x16x32_bf16(afr[0], bfr, acc[0][n], 0, 0, 0);
            acc[1][n] = __builtin_amdgcn_mfma_f32_16x16x32_bf16(afr[1], bfr, acc[1][n], 0, 0, 0);
        }
    }
    __syncthreads();   // all BqF reads done before Xn (overlaid) m_aggr writes

#pragma unroll
    for (int mi = 0; mi < 2; mi++) {
        int q = wid * 2 + mi;
        int ebase = q * 16;
        float cmr[4];
#pragma unroll
        for (int r = 0; r < 4; r++) cmr[r] = scm[ebase + quad * 4 + r];
        float apc[4][OUTT];
#pragma unroll
        for (int r = 0; r < 4; r++)
#pragma unroll
            for (int t = 0; t < OUTT; t++) apc[r][t] = 0.f;
#pragma unroll
        for (int n = 0; n < 8; n++) {
            int f = n * 16 + c;
            float be2v = b2v[f];
            float wcv[OUTT];
            if (FIN) {
#pragma unroll
                for (int t = 0; t < OUTT; t++) wcv[t] = Wc[f * 5 + t];
            } else {
                wcv[0] = Wc[f];
            }
            float cs = 0.f;
#pragma unroll
            for (int r = 0; r < 4; r++) {
                float v = silu_f(acc[mi][n][r] + be2v) * cmr[r];
                cs += v;
#pragma unroll
                for (int t = 0; t < OUTT; t++) apc[r][t] += v * wcv[t];
            }
            cs += __shfl_xor(cs, 16, 64);
            cs += __shfl_xor(cs, 32, 64);
            if (!FIN && lane < 16)
                *(short*)((char*)Xn + ((q * 512 + (128 + f) * 2) ^ ((q & 7) << 4))) =
                    f2bf(cs * 0.0625f);
        }
#pragma unroll
        for (int t = 0; t < OUTT; t++) {
#pragma unroll
            for (int r = 0; r < 4; r++) {
                float v = apc[r][t];
                v += __shfl_xor(v, 1, 64);
                v += __shfl_xor(v, 2, 64);
                v += __shfl_xor(v, 4, 64);
                v += __shfl_xor(v, 8, 64);
                if (c == 0) scoef[(ebase + quad * 4 + r) * OUTT + t] = v;
            }
        }
    }
    __syncthreads();   // scoef + Xn m_aggr ready; lwsT K-loop reads done

    if (tid < QB * 3 * OUTT) {
        int qq = tid / (3 * OUTT), rem = tid % (3 * OUTT), t = rem / 3, c2 = rem % 3;
        float cbv = cbp[t];
        float s = 0.f;
#pragma unroll 4
        for (int r = 0; r < 16; r++) {
            int ee = qq * 16 + r;
            s += (scoef[ee * OUTT + t] + cbv) * sdir[c2 * EB + ee];
        }
        float dd = s * 0.0625f;
        if (FIN) out[(q0 + qq) * 15 + t * 3 + c2] = xs[qq * 3 + c2] + dd - qp[(q0 + qq) * 3 + c2];
        else xs[qq * 3 + c2] = xs[qq * 3 + c2] + dd;
    }
    if (FIN) return;

    // ---- node MLP (block-local) ----
    // stage h (regs -> bf16) into Xn k0..127
    {
        int q = tid >> 5, f0 = (tid & 31) * 4;
        shortx4 v;
        v[0] = f2bf(hreg.x); v[1] = f2bf(hreg.y); v[2] = f2bf(hreg.z); v[3] = f2bf(hreg.w);
        *(shortx4*)((char*)Xn + ((q * 512 + f0 * 2) ^ ((q & 7) << 4))) = v;
    }
    stageB512(lwsT, nW1T + L * 32768, 32, 0, tid);     // Wn1 k-half 0 (h)
    __syncthreads();

    floatx4 acc1 = (floatx4)0.f;
    gemm16(Xn, lwsT, acc1, 0, wid, quad, c, swz);      // GEMM1a: h-half
    __syncthreads();
    stageB512(lwsT, nW1T + L * 32768, 32, 16, tid);    // Wn1 k-half 1 (m_aggr)
    __syncthreads();
    gemm16(Xn, lwsT, acc1, 128, wid, quad, c, swz);    // GEMM1b (accumulate)
    __syncthreads();                                    // Xn k128 reads done

    {
        int f = wid * 16 + c;
        float b1v = nb1all[L * 128 + f];
#pragma unroll
        for (int r = 0; r < 4; r++) {
            int q = quad * 4 + r;
            *(short*)((char*)Xn + ((q * 512 + (128 + f) * 2) ^ ((q & 7) << 4))) =
                f2bf(silu_f(acc1[r] + b1v));
        }
    }
    stageB512(lwsT, nW2T + L * 16384, 16, 0, tid);
    __syncthreads();

    floatx4 acc2 = (floatx4)0.f;
    gemm16(Xn, lwsT, acc2, 128, wid, quad, c, swz);    // GEMM2: S · Wn2
    __syncthreads();                                    // lwsT reads done

    {
        int f = wid * 16 + c;
        float b2 = nb2all[L * 128 + f];
#pragma unroll
        for (int r = 0; r < 4; r++)
            delta[(quad * 4 + r) * 128 + f] = acc2[r] + b2;
    }
    stageB512(lwsT, W1midT + L * 16384, 16, 0, tid);
    __syncthreads();

    {   // owner updates h register, writes bf16(h') to Xn k0..127
        int q = tid >> 5, f0 = (tid & 31) * 4;
        hreg.x += delta[q * 128 + f0 + 0];
        hreg.y += delta[q * 128 + f0 + 1];
        hreg.z += delta[q * 128 + f0 + 2];
        hreg.w += delta[q * 128 + f0 + 3];
        shortx4 v;
        v[0] = f2bf(hreg.x); v[1] = f2bf(hreg.y); v[2] = f2bf(hreg.z); v[3] = f2bf(hreg.w);
        *(shortx4*)((char*)Xn + ((q * 512 + f0 * 2) ^ ((q & 7) << 4))) = v;
    }
    __syncthreads();

    floatx4 acc3 = (floatx4)0.f;
    gemm16(Xn, lwsT, acc3, 0, wid, quad, c, swz);      // GEMM3: h' · W1mid
    __syncthreads();                                    // Xn reads done before BqF overlay write
    {
        int f = wid * 16 + c;
#pragma unroll
        for (int r = 0; r < 4; r++)
            BqF[(quad * 4 + r) * 128 + f] = acc3[r];
    }
    __syncthreads();                                    // end of layer: xs/BqF/lwsT ready
}

// ---------------- mega kernel: all 4 edge layers + node MLPs for 16 queries ----------------
// launch_bounds (512,2) is THE validated config: VGPR=128, WRITE ~1MB (no spill), 243.5us.
// (512,3) -> VGPR 84 spilled 148MB (round 17); (512,4) -> VGPR 64 spilled 222MB (rounds 11/14).
// Occupancy is pinned: >=128 regs needed (else spill) caps 16 waves/CU; LDS caps 2 blocks.
__global__ __launch_bounds__(512, 2) void k_mega(
    const float* __restrict__ Agall, const float* __restrict__ eW1,
    const short* __restrict__ wsT,
    const float* __restrict__ eb2, const float* __restrict__ cW,
    const float* __restrict__ cb,
    const float* __restrict__ fcW, const float* __restrict__ fcb,
    const int* __restrict__ erow, const float* __restrict__ gridp,
    const float* __restrict__ qp, float* __restrict__ out,
    const float* __restrict__ nb1, const float* __restrict__ nb2,
    const short* __restrict__ nW1T, const short* __restrict__ nW2T,
    const short* __restrict__ W1midT) {
    __shared__ float misc[2560];       // 10.25KB scratch (delta overlays)
    __shared__ float xs[48];
    __shared__ int sgi[256];
    __shared__ union { short xn[16 * 256]; float bq[16 * 128]; } XB;  // 8KB overlay
    __shared__ short lwsT[HD * HD];    // 32KB
    int tid = threadIdx.x;
    // XCD-chunked swizzle (bijective: EBLK % 8 == 0)
    int sb = (blockIdx.x & 7) * (EBLK / 8) + (blockIdx.x >> 3);
    int q0 = sb * QB;

    if (tid < QB * 3) xs[tid] = qp[q0 * 3 + tid];
    if (tid < EB) sgi[tid] = erow[q0 * DEG + tid] - N_PTS;
    for (int i = tid; i < 16 * 128; i += 512) XB.bq[i] = 0.0f;   // Bq(0) = 0
    float4 hreg = make_float4(0.f, 0.f, 0.f, 0.f);               // h(0) = 0
    __syncthreads();

    for (int L = 0; L < 3; L++)
        edge_layer<1, false>(L, q0, tid, hreg, misc, xs, sgi, XB.xn, XB.bq, lwsT,
                             Agall, eW1, wsT, eb2, cW, cb, fcW, fcb, gridp, qp, out,
                             nb1, nb2, nW1T, nW2T, W1midT);
    edge_layer<5, true>(3, q0, tid, hreg, misc, xs, sgi, XB.xn, XB.bq, lwsT,
                        Agall, eW1, wsT, eb2, cW, cb, fcW, fcb, gridp, qp, out,
                        nb1, nb2, nW1T, nW2T, W1midT);
}

extern "C" void kernel_launch(void* const* d_in, const int* in_sizes, int n_in,
                              void* d_out, int out_size, void* d_ws, size_t ws_size,
                              hipStream_t stream) {
    float* out = (float*)d_out;
    int fill_blocks = (out_size + 255) / 256;

    static const int exp_sz[16] = { 49152, 524288, 1536, 131584, 512, 65536, 512, 384,
                                    3, 640, 5, 131072, 512, 65536, 512, 524288 };
    bool ok = (n_in == 16);
    for (int i = 0; ok && i < 16; i++) if (in_sizes[i] != exp_sz[i]) ok = false;
    if (!ok || ws_size < (size_t)40 * 1024 * 1024) {
        k_fillf<<<fill_blocks, 256, 0, stream>>>(out, 777.0f, out_size);
        return;
    }

    const float* qp    = (const float*)d_in[0];
    const float* codes = (const float*)d_in[1];
    const float* gridp = (const float*)d_in[2];
    const float* eW1   = (const float*)d_in[3];
    const float* eb1   = (const float*)d_in[4];
    const float* eW2   = (const float*)d_in[5];
    const float* eb2   = (const float*)d_in[6];
    const float* cW    = (const float*)d_in[7];
    const float* cb    = (const float*)d_in[8];
    const float* fcW   = (const float*)d_in[9];
    const float* fcb   = (const float*)d_in[10];
    const float* nW1   = (const float*)d_in[11];
    const float* nb1   = (const float*)d_in[12];
    const float* nW2   = (const float*)d_in[13];
    const float* nb2   = (const float*)d_in[14];
    const int*   erow  = (const int*)d_in[15];

    float* ws = (float*)d_ws;
    float* Agall = ws;  ws += 4 * N_GRID * HD;
    short* wsT    = (short*)ws;        // 4 x 16384
    short* nW1T   = wsT + 65536;       // 3 x 32768
    short* nW2T   = nW1T + 98304;      // 3 x 16384
    short* W1midT = nW2T + 49152;      // 3 x 16384
    short* W1topT = W1midT + 49152;    // 4 x 16384

    k_prepAll<<<(65536 + 3 * 32768 + 6 * 16384 + 4 * 16384 + 255) / 256, 256, 0, stream>>>(
        eW2, nW1, nW2, eW1, wsT, nW1T, nW2T, W1midT, W1topT);

    // fused grid-node pipeline: one launch, all 4 layers, 256 blocks (full GPU)
    k_gm<<<N_GRID / 16, 256, 0, stream>>>(codes, Agall, W1topT, eb1,
                                          nW1T, nb1, nW2T, nb2);

    // one launch: all 4 edge layers + node MLPs (per-query state block-local)
    k_mega<<<EBLK, 512, 0, stream>>>(
        Agall, eW1, wsT, eb2, cW, cb, fcW, fcb, erow, gridp, qp, out,
        nb1, nb2, nW1T, nW2T, W1midT);
}